// Round 1
// 178.757 us; speedup vs baseline: 1.0229x; 1.0229x over previous
//
#include <hip/hip_runtime.h>

// Embedding gather: out[t, :] = e[token_ids[t], :]
// token_ids: (2,4096) int32 -> 8192 tokens
// e: (32000, 1024) float32
// out: (2, 4096, 1024) float32
//
// 8 tokens per 256-thread block (grid = 1024): each thread moves one 16B
// vector per token, 8 independent gathers in flight per wave (2x the MLP of
// the previous version at the same total outstanding-load count), half the
// waves -> less launch ramp/tail. Non-temporal stores keep the write-once
// output from evicting embedding rows from L2. Native ext_vector_type so
// __builtin_nontemporal_store accepts it.

#define DIM 1024
#define TOK_PER_BLOCK 8

typedef float f32x4 __attribute__((ext_vector_type(4)));

__global__ __launch_bounds__(256) void embedding_gather_kernel(
    const int* __restrict__ ids,
    const float* __restrict__ e,
    float* __restrict__ out,
    int n_tokens)
{
    const int t0 = blockIdx.x * TOK_PER_BLOCK;
    const int tid = threadIdx.x;

    // Wave-uniform row indices (compiler scalarizes: s_load, one dependency
    // round-trip shared by all 8 gathers)
    int rows[TOK_PER_BLOCK];
#pragma unroll
    for (int i = 0; i < TOK_PER_BLOCK; ++i)
        rows[i] = ids[t0 + i];

    // 8 independent 16B gather loads in flight before any wait
    f32x4 v[TOK_PER_BLOCK];
#pragma unroll
    for (int i = 0; i < TOK_PER_BLOCK; ++i) {
        const f32x4* src = (const f32x4*)(e + (size_t)rows[i] * DIM);
        v[i] = src[tid];
    }

    // Non-temporal stores: output is write-once, keep it out of L2.
    // Compiler interleaves these with the load completions (vmcnt(N)).
#pragma unroll
    for (int i = 0; i < TOK_PER_BLOCK; ++i) {
        f32x4* dst = (f32x4*)(out + (size_t)(t0 + i) * DIM);
        __builtin_nontemporal_store(v[i], dst + tid);
    }
}

extern "C" void kernel_launch(void* const* d_in, const int* in_sizes, int n_in,
                              void* d_out, int out_size, void* d_ws, size_t ws_size,
                              hipStream_t stream)
{
    const int* ids = (const int*)d_in[0];     // (2,4096) int32
    const float* e = (const float*)d_in[1];   // (32000,1024) fp32
    float* out = (float*)d_out;               // (2,4096,1024) fp32

    const int n_tokens = in_sizes[0];          // 8192
    const int grid = n_tokens / TOK_PER_BLOCK; // 1024

    embedding_gather_kernel<<<grid, 256, 0, stream>>>(ids, e, out, n_tokens);
}